// Round 10
// baseline (149.861 us; speedup 1.0000x reference)
//
#include <hip/hip_runtime.h>

#define IMG_W 512
#define IMG_H 512
#define BATCH 64
#define BAND 16
#define BANDS (IMG_H / BAND)        // 32 bands/image
#define NBLOCKS (BATCH * BANDS)     // 2048 blocks x 256 threads
#define NPIX (BATCH * IMG_W * IMG_H)
#define NSLOT 6
#define SLOT_F 1024                 // floats/slot: [0,512)=p row, [512,1024)=t row

__device__ __forceinline__ float fast_sqrtf(float x) {
    return __builtin_amdgcn_sqrtf(x);
}

// R9 design: DMA ring. global_load_lds consumes no VGPRs -> the compiler
// cannot sink/serialize it (R4-R9 lesson: every register-prefetch scheme got
// flattened; R8/R9 VGPR=76 proved it). Ring of 6 row-pair groups (4KB each,
// 24.6KB LDS -> 6 blocks/CU), raw s_barrier asm (NOT __syncthreads: that
// emits s_waitcnt vmcnt(0) and drains the prefetch queue - the R7/m97
// stall). Flow control: my own s_waitcnt vmcnt(2), so 2 groups/wave (8KB)
// stay in flight across barriers. Every wave issues exactly 1 DMA per
// stage() call (uniform vmcnt counts); OOB rows are clamped at DMA and
// zero-masked in registers at compute.
__global__ __launch_bounds__(256, 6) void sobel_loss_kernel(
    const float* __restrict__ yp, const float* __restrict__ yt,
    float* __restrict__ bsums)
{
    __shared__ __align__(16) float lds[NSLOT * SLOT_F];
    __shared__ float wred[4];

    const int tid  = threadIdx.x;
    const int lane = tid & 63;
    const int wv   = tid >> 6;            // 0..3
    const int bid  = blockIdx.x;
    const int b    = bid >> 5;            // image (32 bands/image)
    const int y0   = (bid & 31) * BAND;

    const float* imgp = yp + ((size_t)b << 18);
    const float* imgt = yt + ((size_t)b << 18);

    // Stage group rel R (input rows y0+R of both images) into slot (R+1)%6.
    // Wave wv DMAs 1KB: image wv>>1, half-row wv&1. Row index clamped
    // (OOB content fixed at compute via register masking).
    auto stage = [&](int R) {
        int slot = (R + 1) % NSLOT;
        int g = y0 + R;
        g = g < 0 ? 0 : (g > IMG_H - 1 ? IMG_H - 1 : g);
        int im = wv >> 1, hf = wv & 1;
        const float* src = (im ? imgt : imgp) +
                           ((size_t)g << 9) + (hf << 8) + (lane << 2);
        float* dst = &lds[slot * SLOT_F + im * 512 + (hf << 8)];
        __builtin_amdgcn_global_load_lds(
            (const __attribute__((address_space(1))) void*)src,
            (__attribute__((address_space(3))) void*)dst, 16, 0, 0);
    };

#define RAW_BARRIER() asm volatile("s_waitcnt lgkmcnt(0)\ns_barrier" ::: "memory")
#define WAIT_VM2()    asm volatile("s_waitcnt vmcnt(2)" ::: "memory")

    // ---- Prologue: 6 groups in flight, wait until 4 landed ----
    stage(-1); stage(0); stage(1); stage(2); stage(3); stage(4);
    WAIT_VM2();
    RAW_BARRIER();

    const int row_sel = tid >> 7;          // 0/1: which of the 2 rows/step
    const int half    = (tid >> 6) & 1;    // 0 = left half-row, 1 = right
    const int x0      = (tid & 127) << 2;  // cols x0..x0+3
    const int px_seam = half ? 255 : 256;  // wave-uniform seam column

    float lsum = 0.f;

    for (int s = 0; s < 8; ++s) {
        const int yo = y0 + 2 * s + row_sel;        // output row
        const int rb = 2 * s + row_sel;             // rel+1 of window top
        const int slA = rb % NSLOT;                 // row yo-1
        const int slB = (rb + 1) % NSLOT;           // row yo
        const int slC = (rb + 2) % NSLOT;           // row yo+1
        const bool zA = (yo == 0);                  // wave-uniform masks
        const bool zC = (yo == IMG_H - 1);

        float mag[2][4];
#pragma unroll
        for (int im = 0; im < 2; ++im) {
            const int off = im * 512;
            const float* rA = &lds[slA * SLOT_F + off];
            const float* rB = &lds[slB * SLOT_F + off];
            const float* rC = &lds[slC * SLOT_F + off];
            float4 a = *(const float4*)(rA + x0);
            float4 m = *(const float4*)(rB + x0);
            float4 c = *(const float4*)(rC + x0);
            float sa = rA[px_seam], sb = rB[px_seam], sc = rC[px_seam];
            if (zA) { a.x = a.y = a.z = a.w = 0.f; sa = 0.f; }
            if (zC) { c.x = c.y = c.z = c.w = 0.f; sc = 0.f; }

            // column sums (1-2-1 vertical) and row diff (C - A)
            float cs0 = fmaf(2.f, m.x, a.x) + c.x;
            float cs1 = fmaf(2.f, m.y, a.y) + c.y;
            float cs2 = fmaf(2.f, m.z, a.z) + c.z;
            float cs3 = fmaf(2.f, m.w, a.w) + c.w;
            float dd0 = c.x - a.x, dd1 = c.y - a.y;
            float dd2 = c.z - a.z, dd3 = c.w - a.w;
            float seam_cs = fmaf(2.f, sb, sa) + sc;
            float seam_d  = sc - sa;

            // halos from neighbor lanes; seam / image edge via uniform data
            float cl = __shfl_up(cs3, 1, 64);
            float cr = __shfl_down(cs0, 1, 64);
            float dl = __shfl_up(dd3, 1, 64);
            float dr = __shfl_down(dd0, 1, 64);
            if (lane == 0)  { cl = half ? seam_cs : 0.f; dl = half ? seam_d : 0.f; }
            if (lane == 63) { cr = half ? 0.f : seam_cs; dr = half ? 0.f : seam_d; }

            const float C6[6] = {cl, cs0, cs1, cs2, cs3, cr};
            const float D6[6] = {dl, dd0, dd1, dd2, dd3, dr};
#pragma unroll
            for (int i = 0; i < 4; ++i) {
                float gv = C6[i + 2] - C6[i];
                float gh = fmaf(2.f, D6[i + 1], D6[i]) + D6[i + 2];
                mag[im][i] = fast_sqrtf(fmaf(gv, gv, fmaf(gh, gh, 1e-18f)));
            }
        }
#pragma unroll
        for (int i = 0; i < 4; ++i)
            lsum += fabsf(mag[1][i] - mag[0][i]); // == sqrt(d^2+eps)*(d^2!=0)

        if (s < 7) {
            RAW_BARRIER();                 // all waves done reading
            stage(2 * s + 5);              // refill freed slots (clamped rows;
            stage(2 * s + 6);              //  uniform vmcnt bookkeeping)
            WAIT_VM2();                    // groups for step s+1 have landed
            RAW_BARRIER();                 // ...in every wave's quarter
        }
    }
#undef RAW_BARRIER
#undef WAIT_VM2

    // ---- Block reduction ----
#pragma unroll
    for (int off = 32; off > 0; off >>= 1)
        lsum += __shfl_down(lsum, off, 64);
    if (lane == 0) wred[wv] = lsum;
    __syncthreads();
    if (tid == 0)
        bsums[bid] = wred[0] + wred[1] + wred[2] + wred[3];
}

__global__ __launch_bounds__(256) void reduce_final(
    const float* __restrict__ bsums, float* __restrict__ out)
{
    __shared__ float wred[4];
    const int tid = threadIdx.x;
    float s = 0.f;
    for (int i = tid; i < NBLOCKS; i += 256) s += bsums[i];
#pragma unroll
    for (int off = 32; off > 0; off >>= 1)
        s += __shfl_down(s, off, 64);
    if ((tid & 63) == 0) wred[tid >> 6] = s;
    __syncthreads();
    if (tid == 0)
        out[0] = (wred[0] + wred[1] + wred[2] + wred[3]) * (1.0f / (float)NPIX);
}

extern "C" void kernel_launch(void* const* d_in, const int* in_sizes, int n_in,
                              void* d_out, int out_size, void* d_ws, size_t ws_size,
                              hipStream_t stream) {
    const float* yp = (const float*)d_in[0];
    const float* yt = (const float*)d_in[1];
    float* out = (float*)d_out;

    float* bsums = (float*)d_ws;   // 8 KB of workspace
    sobel_loss_kernel<<<NBLOCKS, 256, 0, stream>>>(yp, yt, bsums);
    reduce_final<<<1, 256, 0, stream>>>(bsums, out);
}

// Round 11
// 145.162 us; speedup vs baseline: 1.0324x; 1.0324x over previous
//
#include <hip/hip_runtime.h>

#define IMG_W 512
#define IMG_H 512
#define BATCH 64
#define SLAB_ROWS 16
#define SLABS (IMG_H / SLAB_ROWS)   // 32 slabs/image
#define NBLOCKS (BATCH * SLABS)     // 2048 blocks x 256 threads
#define NPIX (BATCH * IMG_W * IMG_H)

__device__ __forceinline__ float fast_sqrtf(float x) {
    return __builtin_amdgcn_sqrtf(x);
}

// FINAL (R8 reproduction — campaign minimum at 43.2-44.5 us kernel time).
// One self-contained task per thread: 4 out rows x 8 cols from 6 input rows
// x 2 images = 24 float4 loads, then compute. Campaign evidence (R4-R10):
// six structurally distinct designs (reg pipelines of depth 2/5, asm-ordered
// batches, LDS double-buffer, global_load_lds DMA ring) all plateau at
// 43-52 us with delivered-to-CU traffic pinned at ~3.3-4.6 TB/s — the read-
// stream rate of the measured copy ceiling (m13: 6.29 TB/s total ~ 3.15 read
// + 3.15 write). Duration is invariant to occupancy (10-66%) and to nominal
// in-flight bytes because the compiler re-sinks register prefetch batches
// (VGPR=76 here proves the 24-load batch is serialized into load/wait/
// compute chains) and DMA variants pay barrier pacing instead. 128 MB demand
// / ~3.15 TB/s read-delivery ~= 41 us floor; this kernel sits ~93% of it.
// All register indices compile-time constants (R3 lesson: dynamic indices
// -> scratch spill, 131 MB of write traffic).

// 10-wide window from two float4 + shfl halo (image x-edges -> 0).
#define MKWIN(W, A, B)                                                         \
    float W[10];                                                               \
    {                                                                          \
        float l_ = __shfl_up((B).w, 1, 64);                                    \
        float r_ = __shfl_down((A).x, 1, 64);                                  \
        W[0] = (lane == 0) ? 0.f : l_;                                         \
        W[1] = (A).x; W[2] = (A).y; W[3] = (A).z; W[4] = (A).w;                \
        W[5] = (B).x; W[6] = (B).y; W[7] = (B).z; W[8] = (B).w;                \
        W[9] = (lane == 63) ? 0.f : r_;                                        \
    }

// horizontal 1-2-1 sums of one row (8 wide)
#define MKHS(HS, W)                                                            \
    float HS[8];                                                               \
    _Pragma("unroll")                                                          \
    for (int j = 0; j < 8; ++j)                                                \
        HS[j] = fmaf(2.f, W[j + 1], W[j]) + W[j + 2];

// one output row O: rows WA(y-1), WB(y), WC(y+1)
#define DO_OUT(O, WA, WB, WC, HSA, HSC, MAG)                                   \
    {                                                                          \
        float c_[10];                                                          \
        _Pragma("unroll")                                                      \
        for (int k = 0; k < 10; ++k)                                           \
            c_[k] = fmaf(2.f, WB[k], WA[k]) + WC[k];                           \
        _Pragma("unroll")                                                      \
        for (int j = 0; j < 8; ++j) {                                          \
            float gh = HSC[j] - HSA[j];                                        \
            float gv = c_[j + 2] - c_[j];                                      \
            MAG[O][j] = fast_sqrtf(fmaf(gv, gv, fmaf(gh, gh, 1e-18f)));        \
        }                                                                      \
    }

// Sobel magnitudes, 4 output rows x 8 cols, from 6 rows (12 float4).
#define SOBEL_IMG(MAG, A0, B0, A1, B1, A2, B2, A3, B3, A4, B4, A5, B5)         \
    {                                                                          \
        MKWIN(w0_, A0, B0) MKWIN(w1_, A1, B1) MKWIN(w2_, A2, B2)               \
        MKWIN(w3_, A3, B3) MKWIN(w4_, A4, B4) MKWIN(w5_, A5, B5)               \
        MKHS(h0_, w0_) MKHS(h1_, w1_) MKHS(h2_, w2_)                           \
        MKHS(h3_, w3_) MKHS(h4_, w4_) MKHS(h5_, w5_)                           \
        DO_OUT(0, w0_, w1_, w2_, h0_, h2_, MAG)                                \
        DO_OUT(1, w1_, w2_, w3_, h1_, h3_, MAG)                                \
        DO_OUT(2, w2_, w3_, w4_, h2_, h4_, MAG)                                \
        DO_OUT(3, w3_, w4_, w5_, h3_, h5_, MAG)                                \
    }

// Load input row ty-1+I (y clamped; OOB rows zeroed after, wave-uniformly).
#define LOADR(I, A, B, IMG)                                                    \
    float4 A, B;                                                               \
    {                                                                          \
        int yy = ty - 1 + (I);                                                 \
        int yc = yy < 0 ? 0 : (yy > IMG_H - 1 ? IMG_H - 1 : yy);               \
        const float* r_ = (IMG) + ((size_t)yc << 9) + x0;                      \
        A = *(const float4*)r_;                                                \
        B = *(const float4*)(r_ + 4);                                          \
    }

__global__ __launch_bounds__(256) void sobel_loss_kernel(
    const float* __restrict__ yp, const float* __restrict__ yt,
    float* __restrict__ bsums)
{
    __shared__ float wred[4];

    const int tid  = threadIdx.x;
    const int lane = tid & 63;
    const int bid  = blockIdx.x;
    const int b    = bid >> 5;                      // image (32 slabs/image)
    const int slab = bid & (SLABS - 1);
    const int ty   = slab * SLAB_ROWS + ((tid >> 6) << 2);  // wave-uniform
    const int x0   = lane << 3;                     // cols x0..x0+7

    const float* imgp = yp + ((size_t)b << 18);
    const float* imgt = yt + ((size_t)b << 18);

    // ---- Issue all 24 loads back-to-back ----
    LOADR(0, A0p, B0p, imgp) LOADR(1, A1p, B1p, imgp) LOADR(2, A2p, B2p, imgp)
    LOADR(3, A3p, B3p, imgp) LOADR(4, A4p, B4p, imgp) LOADR(5, A5p, B5p, imgp)
    LOADR(0, A0t, B0t, imgt) LOADR(1, A1t, B1t, imgt) LOADR(2, A2t, B2t, imgt)
    LOADR(3, A3t, B3t, imgt) LOADR(4, A4t, B4t, imgt) LOADR(5, A5t, B5t, imgt)

    // 'SAME' zero padding for y-edge rows (wave-uniform branches)
    const float4 z4 = {0.f, 0.f, 0.f, 0.f};
    if (ty == 0)            { A0p = z4; B0p = z4; A0t = z4; B0t = z4; }
    if (ty + 4 == IMG_H)    { A5p = z4; B5p = z4; A5t = z4; B5t = z4; }

    // ---- Compute ----
    float magp[4][8], magt[4][8];
    SOBEL_IMG(magp, A0p, B0p, A1p, B1p, A2p, B2p, A3p, B3p, A4p, B4p, A5p, B5p)
    SOBEL_IMG(magt, A0t, B0t, A1t, B1t, A2t, B2t, A3t, B3t, A4t, B4t, A5t, B5t)

    float lsum = 0.f;
#pragma unroll
    for (int o = 0; o < 4; ++o)
#pragma unroll
        for (int j = 0; j < 8; ++j)
            lsum += fabsf(magt[o][j] - magp[o][j]); // == sqrt(d^2+eps)*(d^2!=0)

    // ---- Block reduction ----
#pragma unroll
    for (int off = 32; off > 0; off >>= 1)
        lsum += __shfl_down(lsum, off, 64);
    if (lane == 0) wred[tid >> 6] = lsum;
    __syncthreads();
    if (tid == 0)
        bsums[bid] = wred[0] + wred[1] + wred[2] + wred[3];
}

__global__ __launch_bounds__(256) void reduce_final(
    const float* __restrict__ bsums, float* __restrict__ out)
{
    __shared__ float wred[4];
    const int tid = threadIdx.x;
    float s = 0.f;
    for (int i = tid; i < NBLOCKS; i += 256) s += bsums[i];
#pragma unroll
    for (int off = 32; off > 0; off >>= 1)
        s += __shfl_down(s, off, 64);
    if ((tid & 63) == 0) wred[tid >> 6] = s;
    __syncthreads();
    if (tid == 0)
        out[0] = (wred[0] + wred[1] + wred[2] + wred[3]) * (1.0f / (float)NPIX);
}

extern "C" void kernel_launch(void* const* d_in, const int* in_sizes, int n_in,
                              void* d_out, int out_size, void* d_ws, size_t ws_size,
                              hipStream_t stream) {
    const float* yp = (const float*)d_in[0];
    const float* yt = (const float*)d_in[1];
    float* out = (float*)d_out;

    float* bsums = (float*)d_ws;   // 8 KB of workspace
    sobel_loss_kernel<<<NBLOCKS, 256, 0, stream>>>(yp, yt, bsums);
    reduce_final<<<1, 256, 0, stream>>>(bsums, out);
}